// Round 10
// baseline (445.268 us; speedup 1.0000x reference)
//
#include <hip/hip_runtime.h>
#include <stdint.h>
#include <stddef.h>

// ---------------------------------------------------------------------------
// Neural SDE: B=2048 paths, 64 Euler-Maruyama steps.
// R21 = R20 (360.5us, passing) + ONE change: s_setprio(1)/(0) around each
// pure-MFMA quad in the drift + diffusion phases (T5). Evidence base:
//  - critical path is latency structure, NOT: HBM 1.7% / MFMA 11% / VALU
//    (R18: -2pp, no dt) / bank conflicts (R20: +33%, no dt) / exchange bytes
//    (R13: -60%, no dt) / sync shape (R13/15/16/17 all regressed)
//  - diffusion phase has wave role-diversity (waves 0-1 drift late-join;
//    2-7 in tanh epilogues while others issue MFMA) -> T5's regime
// Pre-commit: neutral result => decomposition converged (latency-bound floor
// ~5.6us/step from serial 3-layer MLP + pair-exchange round-trip).
// ---------------------------------------------------------------------------

typedef __attribute__((ext_vector_type(8))) short bf16x8;   // 8 x bf16 (4 VGPR)
typedef __attribute__((ext_vector_type(4))) float f32x4;    // MFMA C/D
typedef __attribute__((ext_vector_type(4))) int   i32x4;    // 16B copies

#define BB 16
#define NWG 256
#define YST 72    // LD_Y / LD_DB row stride in f32

// ---- ws layout (bytes), all bf16 fragment-swizzled weights --------------
#define WS_WI0 0        // 8 frags   (128x32  K=32  KI=1 NT=8)
#define WS_WI1 8192     // 32 frags  (128x128)
#define WS_WI2 40960    // 16 frags  (64x128)
#define WS_WV0 57344    // 16 frags  (128x64, t-col dropped)
#define WS_WV1 73728    // 32 frags
#define WS_WV2 106496   // 16 frags
#define WS_WC0 122880   // 16 frags
#define WS_WC1 139264   // 32 frags
#define WS_WC2 172032   // 512 frags (2048x128) = 512 KB
#define WS_TV0 696320   // Wv0[:,0] f32 [128]
#define WS_TC0 696832   // Wc0[:,0] f32 [128]
// ---- exchange region: 512 slots x 2048 B ((pid,role,parity)) + flags ----
#define WS_XCHG 700416
#define WS_FLAG 2273280   // 512 x u32 (zeroed by prep each launch)

// ---- LDS layout (bytes) --------------------------------------------------
#define LD_WV0 0        // 16384
#define LD_WV1 16384    // 32768
#define LD_WC0 49152    // 16384
#define LD_WC1 65536    // 32768
#define LD_YBF 98304    // 2048: y A-frags K=64
#define LD_H1V 100352   // 4096
#define LD_H1C 104448   // 4096
#define LD_H2V 108544   // 4096
#define LD_H2C 112640   // 4096
#define LD_Y   116736   // f32 [16][72] = 4608
#define LD_DB  121344   // f32 [16][72] = 4608
#define LD_BM  125952   // f32 [16][33] = 2112
#define LD_BSC 128064   // u32 [2048]: bc2(bf16) | scale_c(bf16)<<16 per col
#define LD_BEV 136256   // f32 [128]
#define LD_BEC 136768
#define LD_BV1 137280
#define LD_BC1 137792
#define LD_BV2 138304   // f32 [64]
#define LD_SV  138560
#define LD_WR  138816   // f32 [8][68] = 2176 (broadcast reads; 68 fine)
#define LD_BR  140992   // 32
#define LD_WV2 141024   // 8192: role's 2 drift B-tiles
#define LDS_TOTAL 149216   // >80KB => 1 WG/CU (forces 256 WGs == 256 CUs)

__device__ __forceinline__ short f2bf(float f) {
  uint32_t u = __builtin_bit_cast(uint32_t, f);
  uint32_t r = (u + 0x7fffu + ((u >> 16) & 1u)) >> 16;   // RNE
  return (short)r;
}
__device__ __forceinline__ float bf2f(short s) {
  uint32_t u = ((uint32_t)(uint16_t)s) << 16;
  return __builtin_bit_cast(float, u);
}
// HW packed f32->bf16 (RNE), 2 values per instr
__device__ __forceinline__ uint32_t cvtpk(float lo, float hi) {
  uint32_t r;
  asm("v_cvt_pk_bf16_f32 %0, %1, %2" : "=v"(r) : "v"(lo), "v"(hi));
  return r;
}
// clamp-free: e->inf => rcp->0 => +1; e->0 => 1-2 = -1. No NaN path.
__device__ __forceinline__ float tanh_fast(float x) {
  float e = __builtin_amdgcn_exp2f(x * 2.8853900817779268f); // 2*log2(e)
  return __builtin_fmaf(-2.f, __builtin_amdgcn_rcpf(e + 1.f), 1.f);
}
__device__ __forceinline__ float lipswish(float x) {
  float s = __builtin_amdgcn_rcpf(1.f + __builtin_amdgcn_exp2f(-1.4426950408889634f * x));
  return 0.909f * x * s;
}
__device__ __forceinline__ float red16(float x) {
  int v;
  v = __builtin_amdgcn_update_dpp(0, __builtin_bit_cast(int, x), 0xB1, 0xF, 0xF, true);
  x += __builtin_bit_cast(float, v);
  v = __builtin_amdgcn_update_dpp(0, __builtin_bit_cast(int, x), 0x4E, 0xF, 0xF, true);
  x += __builtin_bit_cast(float, v);
  v = __builtin_amdgcn_update_dpp(0, __builtin_bit_cast(int, x), 0x141, 0xF, 0xF, true);
  x += __builtin_bit_cast(float, v);
  v = __builtin_amdgcn_update_dpp(0, __builtin_bit_cast(int, x), 0x140, 0xF, 0xF, true);
  x += __builtin_bit_cast(float, v);
  return x;
}
// write activation element (m,k) into a fragment-swizzled bf16 A-buffer
__device__ __forceinline__ void write_act(char* buf, int m, int k, short v) {
  int addr = ((k >> 5) << 10) + (m + ((k >> 3) & 3) * 16) * 16 + ((k & 7) << 1);
  *(short*)(buf + addr) = v;
}

template<int KF>
__device__ __forceinline__ f32x4 gemm_tile(const char* abase, const char* bbase, int lane) {
  f32x4 acc = {0.f, 0.f, 0.f, 0.f};
#pragma unroll
  for (int k = 0; k < KF; k++) {
    bf16x8 a = *(const bf16x8*)(abase + k * 1024 + lane * 16);
    bf16x8 b = *(const bf16x8*)(bbase + k * 1024 + lane * 16);
    acc = __builtin_amdgcn_mfma_f32_16x16x32_bf16(a, b, acc, 0, 0, 0);
  }
  return acc;
}

// ---------------------------------------------------------------------------
// Prep: f32 weights -> bf16 fragment-swizzled blobs in ws. (+ flag zeroing)
// ---------------------------------------------------------------------------
__global__ __launch_bounds__(256) void prep_kernel(
    const float* Wi0, const float* Wi1, const float* Wi2,
    const float* Wv0, const float* Wv1, const float* Wv2,
    const float* Wc0, const float* Wc1, const float* Wc2, char* ws) {
  int gid = blockIdx.x * 256 + threadIdx.x;
  if (gid < 512) ((unsigned*)(ws + WS_FLAG))[gid] = 0;   // re-arm sync each launch
  if (gid < 680 * 64) {
    int frag = gid >> 6, lane = gid & 63;
    const float* src; int start, KI, srcK, c0;
    if      (frag < 8)   { src = Wi0; start = 0;   KI = 1; srcK = 32;  c0 = 0; }
    else if (frag < 40)  { src = Wi1; start = 8;   KI = 4; srcK = 128; c0 = 0; }
    else if (frag < 56)  { src = Wi2; start = 40;  KI = 4; srcK = 128; c0 = 0; }
    else if (frag < 72)  { src = Wv0; start = 56;  KI = 2; srcK = 65;  c0 = 1; }
    else if (frag < 104) { src = Wv1; start = 72;  KI = 4; srcK = 128; c0 = 0; }
    else if (frag < 120) { src = Wv2; start = 104; KI = 4; srcK = 128; c0 = 0; }
    else if (frag < 136) { src = Wc0; start = 120; KI = 2; srcK = 65;  c0 = 1; }
    else if (frag < 168) { src = Wc1; start = 136; KI = 4; srcK = 128; c0 = 0; }
    else                 { src = Wc2; start = 168; KI = 4; srcK = 128; c0 = 0; }
    int rel = frag - start;
    int nt = rel / KI, ki = rel % KI;
    int n16 = lane & 15, quad = lane >> 4;
    const float* s = src + (nt * 16 + n16) * srcK + c0 + ki * 32 + quad * 8;
    bf16x8 v;
#pragma unroll
    for (int j = 0; j < 8; j++) v[j] = f2bf(s[j]);
    *(bf16x8*)(ws + (size_t)frag * 1024 + lane * 16) = v;
  } else {
    int i = gid - 680 * 64;
    if (i < 128)      ((float*)(ws + WS_TV0))[i] = Wv0[i * 65];
    else if (i < 256) ((float*)(ws + WS_TC0))[i - 128] = Wc0[(i - 128) * 65];
  }
}

// ---------------------------------------------------------------------------
// Main persistent kernel: pair of WGs = 16 batch rows; each WG owns 32 of the
// 64 hidden dims; Wc2 weights live in registers for the whole scan.
// ---------------------------------------------------------------------------
__global__ __launch_bounds__(512, 2)
void sde_kernel(
    const float* ts, const float* init_noise, const float* bm,
    const float* bi0, const float* bi1, const float* bi2,
    const float* bv0, const float* bv1, const float* bv2, const float* scale_v,
    const float* bc0, const float* bc1, const float* bc2, const float* scale_c,
    const float* Wr, const float* br,
    char* ws, float* out) {
  extern __shared__ __align__(16) char lds[];
  const int tid  = threadIdx.x;
  const int lane = tid & 63;
  const int wv   = tid >> 6;     // wave 0..7
  const int nl   = lane & 15;
  const int quad = lane >> 4;
  const int bid  = blockIdx.x;
  const int ro   = (bid >> 3) & 1;                 // role: which h-half we own
  const int pid  = ((bid >> 4) << 3) | (bid & 7);  // pair id 0..127 (partner = same XCD)
  const int b0   = pid * BB;
  const int hbase = ro << 5;                       // own h in [hbase, hbase+32)
  const char* wc2 = ws + WS_WC2 + (size_t)(ro * 64 + wv * 8) * 4096;  // our 8 tiles
  char* xch = ws + WS_XCHG;
  unsigned* flags = (unsigned*)(ws + WS_FLAG);
  const int myflag = (pid << 1) | ro;
  const int paflag = (pid << 1) | (1 - ro);
  const float brv = (tid < 128) ? br[tid & 7] : 0.f;   // finalize bias, hoisted

  // ---- persistent per-thread effective-bias source regs (tids 256..511) ----
  float tvq = 0.f, bbq = 0.f;
  if (tid >= 256) {
    int j = tid - 256;
    if (j < 128) { tvq = ((const float*)(ws + WS_TV0))[j];       bbq = bv0[j]; }
    else         { tvq = ((const float*)(ws + WS_TC0))[j - 128]; bbq = bc0[j - 128]; }
  }

  // ---- stage small weights & params into LDS ----
  {
    const i32x4* s0 = (const i32x4*)(ws + WS_WV0);   // WV0+WV1 = 49152 B
    const i32x4* s1 = (const i32x4*)(ws + WS_WC0);   // WC0+WC1 = 49152 B
    i32x4* d0 = (i32x4*)(lds + LD_WV0);
    i32x4* d1 = (i32x4*)(lds + LD_WC0);
    for (int j = tid; j < 3072; j += 512) { d0[j] = s0[j]; d1[j] = s1[j]; }
  }
  { // role's 2 drift B-tiles (Wv2 cols [hbase, hbase+32)) -> LDS, 8KB
    const i32x4* s2 = (const i32x4*)(ws + WS_WV2 + ro * 8192);
    ((i32x4*)(lds + LD_WV2))[tid] = s2[tid];   // 512 x 16B
  }
  for (int j = tid; j < 2048; j += 512) {   // packed bc2|scale_c per col
    uint32_t u = (uint32_t)(uint16_t)f2bf(bc2[j]) |
                 ((uint32_t)(uint16_t)f2bf(scale_c[j]) << 16);
    ((uint32_t*)(lds + LD_BSC))[j] = u;
  }
  if (tid < 128)      { ((float*)(lds + LD_BV1))[tid] = bv1[tid];
                        ((float*)(lds + LD_BC1))[tid] = bc1[tid]; }
  else if (tid < 192) { int k = tid - 128; ((float*)(lds + LD_BV2))[k] = bv2[k];
                        ((float*)(lds + LD_SV))[k] = scale_v[k]; }
  else if (tid < 200) { int k = tid - 192; ((float*)(lds + LD_BR))[k] = br[k]; }
  { int dd = tid >> 6, k = tid & 63;
    ((float*)(lds + LD_WR))[dd * 68 + k] = Wr[dd * 64 + k]; }
  // init noise -> YBF (K=32)
  { int m = tid >> 5, k = tid & 31;
    write_act(lds + LD_YBF, m, k, f2bf(init_noise[(b0 + m) * 32 + k])); }
  __syncthreads();

  // ---- init MLP: noise -> y0 (duplicated across the pair; LDS-only) ----
  { f32x4 acc = gemm_tile<1>(lds + LD_YBF, ws + WS_WI0 + wv * 1024, lane);
    int col = wv * 16 + nl; float bias = bi0[col];
#pragma unroll
    for (int r = 0; r < 4; r++)
      write_act(lds + LD_H1V, quad * 4 + r, col, f2bf(fmaxf(0.f, acc[r] + bias))); }
  __syncthreads();
  { f32x4 acc = gemm_tile<4>(lds + LD_H1V, ws + WS_WI1 + wv * 4096, lane);
    int col = wv * 16 + nl; float bias = bi1[col];
#pragma unroll
    for (int r = 0; r < 4; r++)
      write_act(lds + LD_H2V, quad * 4 + r, col, f2bf(fmaxf(0.f, acc[r] + bias))); }
  __syncthreads();
  if (wv < 4) {
    f32x4 acc = gemm_tile<4>(lds + LD_H2V, ws + WS_WI2 + wv * 4096, lane);
    int col = wv * 16 + nl; float bias = bi2[col];
#pragma unroll
    for (int r = 0; r < 4; r++)
      ((float*)(lds + LD_Y))[(quad * 4 + r) * YST + col] = acc[r] + bias;
  }
  __syncthreads();

  // ---- one-time load: this wave's 8 Wc2 tiles -> 32 persistent frags ----
#define LOADT(N, OFF)                                                          \
  bf16x8 w##N##a = *(const bf16x8*)(wc2 + (OFF) +    0 + lane * 16);           \
  bf16x8 w##N##b = *(const bf16x8*)(wc2 + (OFF) + 1024 + lane * 16);           \
  bf16x8 w##N##c = *(const bf16x8*)(wc2 + (OFF) + 2048 + lane * 16);           \
  bf16x8 w##N##d = *(const bf16x8*)(wc2 + (OFF) + 3072 + lane * 16);
  LOADT(0, 0)     LOADT(1, 4096)  LOADT(2, 8192)  LOADT(3, 12288)
  LOADT(4, 16384) LOADT(5, 20480) LOADT(6, 24576) LOADT(7, 28672)
#undef LOADT

  // ---- preamble: YBF from Y; bm step0; effective biases step0 ----
  const float ts0 = ts[0];
  for (int e = tid; e < 1024; e += 512) {
    int row = e >> 6, k = e & 63;
    write_act(lds + LD_YBF, row, k, f2bf(((float*)(lds + LD_Y))[row * YST + k]));
  }
  ((float*)(lds + LD_BM))[(tid >> 5) * 33 + (tid & 31)] =
      bm[((size_t)(b0 + (tid >> 5)) * 64 + 0) * 32 + (tid & 31)];
  if (tid >= 256) {
    int j = tid - 256; float v = bbq + ts0 * tvq;
    if (j < 128) ((float*)(lds + LD_BEV))[j] = v;
    else         ((float*)(lds + LD_BEC))[j - 128] = v;
  }
  __syncthreads();

  // ================= 64-step scan =================
  for (int step = 0; step < 64; step++) {
    // ---- L1 (each wave: v and c col-tile wv; full nets, duplicated) ----
    {
      int col = wv * 16 + nl;
      f32x4 av = gemm_tile<2>(lds + LD_YBF, lds + LD_WV0 + wv * 2048, lane);
      f32x4 ac = gemm_tile<2>(lds + LD_YBF, lds + LD_WC0 + wv * 2048, lane);
      float bv = ((float*)(lds + LD_BEV))[col];
      float bc = ((float*)(lds + LD_BEC))[col];
      uint32_t p0 = cvtpk(lipswish(av[0] + bv), lipswish(av[1] + bv));
      uint32_t p1 = cvtpk(lipswish(av[2] + bv), lipswish(av[3] + bv));
      uint32_t q0 = cvtpk(lipswish(ac[0] + bc), lipswish(ac[1] + bc));
      uint32_t q1 = cvtpk(lipswish(ac[2] + bc), lipswish(ac[3] + bc));
      write_act(lds + LD_H1V, quad * 4 + 0, col, (short)p0);
      write_act(lds + LD_H1V, quad * 4 + 1, col, (short)(p0 >> 16));
      write_act(lds + LD_H1V, quad * 4 + 2, col, (short)p1);
      write_act(lds + LD_H1V, quad * 4 + 3, col, (short)(p1 >> 16));
      write_act(lds + LD_H1C, quad * 4 + 0, col, (short)q0);
      write_act(lds + LD_H1C, quad * 4 + 1, col, (short)(q0 >> 16));
      write_act(lds + LD_H1C, quad * 4 + 2, col, (short)q1);
      write_act(lds + LD_H1C, quad * 4 + 3, col, (short)(q1 >> 16));
    }
    __syncthreads();   // B1
    // ---- L2 ----
    {
      int col = wv * 16 + nl;
      f32x4 av = gemm_tile<4>(lds + LD_H1V, lds + LD_WV1 + wv * 4096, lane);
      f32x4 ac = gemm_tile<4>(lds + LD_H1C, lds + LD_WC1 + wv * 4096, lane);
      float bv = ((float*)(lds + LD_BV1))[col];
      float bc = ((float*)(lds + LD_BC1))[col];
      uint32_t p0 = cvtpk(lipswish(av[0] + bv), lipswish(av[1] + bv));
      uint32_t p1 = cvtpk(lipswish(av[2] + bv), lipswish(av[3] + bv));
      uint32_t q0 = cvtpk(lipswish(ac[0] + bc), lipswish(ac[1] + bc));
      uint32_t q1 = cvtpk(lipswish(ac[2] + bc), lipswish(ac[3] + bc));
      write_act(lds + LD_H2V, quad * 4 + 0, col, (short)p0);
      write_act(lds + LD_H2V, quad * 4 + 1, col, (short)(p0 >> 16));
      write_act(lds + LD_H2V, quad * 4 + 2, col, (short)p1);
      write_act(lds + LD_H2V, quad * 4 + 3, col, (short)(p1 >> 16));
      write_act(lds + LD_H2C, quad * 4 + 0, col, (short)q0);
      write_act(lds + LD_H2C, quad * 4 + 1, col, (short)(q0 >> 16));
      write_act(lds + LD_H2C, quad * 4 + 2, col, (short)q1);
      write_act(lds + LD_H2C, quad * 4 + 3, col, (short)(q1 >> 16));
    }
    __syncthreads();   // B2
    // ---- next-step bm: issued here, drains under the long diff phase ----
    float bm_next = 0.f;
    if (step + 1 < 64)
      bm_next = bm[((size_t)(b0 + (tid >> 5)) * 64 + (step + 1)) * 32 + (tid & 31)];
    // ---- L3: drift for own 32 cols (waves 0-1, LDS-staged weights) ----
    if (wv < 2) {
      const char* vb = lds + LD_WV2 + wv * 4096;
      f32x4 acc = {0.f, 0.f, 0.f, 0.f};
      __builtin_amdgcn_s_setprio(1);
      acc = __builtin_amdgcn_mfma_f32_16x16x32_bf16(
          *(const bf16x8*)(lds + LD_H2V +    0 + lane * 16),
          *(const bf16x8*)(vb +    0 + lane * 16), acc, 0, 0, 0);
      acc = __builtin_amdgcn_mfma_f32_16x16x32_bf16(
          *(const bf16x8*)(lds + LD_H2V + 1024 + lane * 16),
          *(const bf16x8*)(vb + 1024 + lane * 16), acc, 0, 0, 0);
      acc = __builtin_amdgcn_mfma_f32_16x16x32_bf16(
          *(const bf16x8*)(lds + LD_H2V + 2048 + lane * 16),
          *(const bf16x8*)(vb + 2048 + lane * 16), acc, 0, 0, 0);
      acc = __builtin_amdgcn_mfma_f32_16x16x32_bf16(
          *(const bf16x8*)(lds + LD_H2V + 3072 + lane * 16),
          *(const bf16x8*)(vb + 3072 + lane * 16), acc, 0, 0, 0);
      __builtin_amdgcn_s_setprio(0);
      int col = (ro * 2 + wv) * 16 + nl;
      float bias = ((float*)(lds + LD_BV2))[col];
      float sv   = ((float*)(lds + LD_SV))[col];
#pragma unroll
      for (int r = 0; r < 4; r++)
        ((float*)(lds + LD_DB))[(quad * 4 + r) * YST + col] = sv * tanh_fast(acc[r] + bias);
    }
    // ---- diffusion: 4 pairs of tiles (own half), weights resident in regs ----
    {
      bf16x8 a0f = *(const bf16x8*)(lds + LD_H2C +    0 + lane * 16);
      bf16x8 a1f = *(const bf16x8*)(lds + LD_H2C + 1024 + lane * 16);
      bf16x8 a2f = *(const bf16x8*)(lds + LD_H2C + 2048 + lane * 16);
      bf16x8 a3f = *(const bf16x8*)(lds + LD_H2C + 3072 + lane * 16);
      const float* bmp = (const float*)(lds + LD_BM);
      float bmr00 = bmp[(quad * 4 + 0) * 33 + nl];
      float bmr01 = bmp[(quad * 4 + 1) * 33 + nl];
      float bmr02 = bmp[(quad * 4 + 2) * 33 + nl];
      float bmr03 = bmp[(quad * 4 + 3) * 33 + nl];
      float bmr10 = bmp[(quad * 4 + 0) * 33 + 16 + nl];
      float bmr11 = bmp[(quad * 4 + 1) * 33 + 16 + nl];
      float bmr12 = bmp[(quad * 4 + 2) * 33 + 16 + nl];
      float bmr13 = bmp[(quad * 4 + 3) * 33 + 16 + nl];
      const uint32_t* bscp = (const uint32_t*)(lds + LD_BSC) + (ro * 64 + wv * 8) * 16 + nl;
      float ps0, ps1, ps2, ps3;

#define DIFF_PAIR(P, E0, E1, E2, E3, O0, O1, O2, O3)                          \
      {  /* even tile 2P */                                                   \
        f32x4 acc = {0.f, 0.f, 0.f, 0.f};                                     \
        __builtin_amdgcn_s_setprio(1);                                        \
        acc = __builtin_amdgcn_mfma_f32_16x16x32_bf16(a0f, E0, acc, 0, 0, 0); \
        acc = __builtin_amdgcn_mfma_f32_16x16x32_bf16(a1f, E1, acc, 0, 0, 0); \
        acc = __builtin_amdgcn_mfma_f32_16x16x32_bf16(a2f, E2, acc, 0, 0, 0); \
        acc = __builtin_amdgcn_mfma_f32_16x16x32_bf16(a3f, E3, acc, 0, 0, 0); \
        __builtin_amdgcn_s_setprio(0);                                        \
        uint32_t bsc = bscp[(2*(P))*16];                                      \
        float bc2v = bf2f((short)(bsc & 0xffffu));                            \
        float scv  = bf2f((short)(bsc >> 16));                                \
        ps0 = tanh_fast(acc[0] + bc2v) * scv * bmr00;                         \
        ps1 = tanh_fast(acc[1] + bc2v) * scv * bmr01;                         \
        ps2 = tanh_fast(acc[2] + bc2v) * scv * bmr02;                         \
        ps3 = tanh_fast(acc[3] + bc2v) * scv * bmr03;                         \
      }                                                                       \
      {  /* odd tile 2P+1 */                                                  \
        f32x4 acc = {0.f, 0.f, 0.f, 0.f};                                     \
        __builtin_amdgcn_s_setprio(1);                                        \
        acc = __builtin_amdgcn_mfma_f32_16x16x32_bf16(a0f, O0, acc, 0, 0, 0); \
        acc = __builtin_amdgcn_mfma_f32_16x16x32_bf16(a1f, O1, acc, 0, 0, 0); \
        acc = __builtin_amdgcn_mfma_f32_16x16x32_bf16(a2f, O2, acc, 0, 0, 0); \
        acc = __builtin_amdgcn_mfma_f32_16x16x32_bf16(a3f, O3, acc, 0, 0, 0); \
        __builtin_amdgcn_s_setprio(0);                                        \
        uint32_t bsc = bscp[(2*(P)+1)*16];                                    \
        float bc2v = bf2f((short)(bsc & 0xffffu));                            \
        float scv  = bf2f((short)(bsc >> 16));                                \
        ps0 += tanh_fast(acc[0] + bc2v) * scv * bmr10;                        \
        ps1 += tanh_fast(acc[1] + bc2v) * scv * bmr11;                        \
        ps2 += tanh_fast(acc[2] + bc2v) * scv * bmr12;                        \
        ps3 += tanh_fast(acc[3] + bc2v) * scv * bmr13;                        \
        ps0 = red16(ps0); ps1 = red16(ps1); ps2 = red16(ps2); ps3 = red16(ps3);\
        if (nl < 4) {                                                         \
          int row = quad * 4 + nl;                                            \
          float s = (nl == 0) ? ps0 : (nl == 1) ? ps1 : (nl == 2) ? ps2 : ps3;\
          ((float*)(lds + LD_Y))[row * YST + (hbase + (wv << 2) + (P))] += s; \
        }                                                                     \
      }

      DIFF_PAIR(0, w0a, w0b, w0c, w0d, w1a, w1b, w1c, w1d)
      DIFF_PAIR(1, w2a, w2b, w2c, w2d, w3a, w3b, w3c, w3d)
      DIFF_PAIR(2, w4a, w4b, w4c, w4d, w5a, w5b, w5c, w5d)
      DIFF_PAIR(3, w6a, w6b, w6c, w6d, w7a, w7b, w7c, w7d)
#undef DIFF_PAIR
    }
    __syncthreads();   // B3
    // ---- M: own-half vnew; YBF own; readout partials; publish; flag ----
    char* my_slot = xch + (size_t)(((myflag << 1) | (step & 1))) * 2048;
    const char* pa_slot = xch + (size_t)(((paflag << 1) | (step & 1))) * 2048;
    float part = 0.f;   // own-half readout partial for (row=tid>>3, dd=tid&7)
    if (tid < 128) {
      int row = tid >> 3, kq = tid & 7;
      int c0 = hbase + kq * 4;
      f32x4 yv = *(const f32x4*)(lds + LD_Y  + (row * YST + c0) * 4);
      f32x4 db = *(const f32x4*)(lds + LD_DB + (row * YST + c0) * 4);
      f32x4 vn = yv + db;
      *(f32x4*)(lds + LD_Y + (row * YST + c0) * 4) = vn;
      uint32_t p0 = cvtpk(vn[0], vn[1]);
      uint32_t p1 = cvtpk(vn[2], vn[3]);
      uint64_t p64 = (uint64_t)p0 | ((uint64_t)p1 << 32);
      int inner = (row + (kq >> 1) * 16) * 16 + ((kq & 1) << 3);  // offset in 1KB K-half
      *(uint64_t*)(lds + LD_YBF + ro * 1024 + inner) = p64;
      __hip_atomic_store((unsigned long long*)(my_slot + inner), (unsigned long long)p64,
                         __ATOMIC_RELAXED, __HIP_MEMORY_SCOPE_AGENT);
      // own-half readout partial (dd = kq): reread updated row (intra-wave:
      // the 8 sibling lanes of this row are in the same wave -> lgkm-ordered)
      const float* yr = (const float*)(lds + LD_Y) + row * YST + hbase;
      const float* wr = (const float*)(lds + LD_WR) + kq * 68 + hbase;
#pragma unroll
      for (int j = 0; j < 8; j++) {
        f32x4 a = *(const f32x4*)(yr + j * 4);
        f32x4 w = *(const f32x4*)(wr + j * 4);
        part = fmaf(a[0], w[0], part); part = fmaf(a[1], w[1], part);
        part = fmaf(a[2], w[2], part); part = fmaf(a[3], w[3], part);
      }
      if ((tid >> 6) != ro)   // publisher wave: rows the PARTNER finalizes
        __hip_atomic_store((unsigned*)(my_slot + 1024) + (tid & 63),
                           __builtin_bit_cast(unsigned, part),
                           __ATOMIC_RELAXED, __HIP_MEMORY_SCOPE_AGENT);
      asm volatile("s_waitcnt vmcnt(0)" ::: "memory");   // wave-scope drain
      if (lane == 0)
        __hip_atomic_store(flags + ((myflag << 1) | (tid >> 6)), (unsigned)(step + 1),
                           __ATOMIC_RELAXED, __HIP_MEMORY_SCOPE_AGENT);
    } else if (tid >= 256 && step + 1 < 64) {
      int j = tid - 256; float v = bbq + (ts0 + (float)(step + 1)) * tvq;
      if (j < 128) ((float*)(lds + LD_BEV))[j] = v;
      else         ((float*)(lds + LD_BEC))[j - 128] = v;
    }
    if (step + 1 < 64)
      ((float*)(lds + LD_BM))[(tid >> 5) * 33 + (tid & 31)] = bm_next;
    // ---- consume partner payload (tid<128): per-thread spin, no barrier ----
    if (tid < 128) {
      unsigned want = (unsigned)(step + 1);
      const unsigned long long* pfl = (const unsigned long long*)(flags + (paflag << 1));
      int guard = 0;
      for (;;) {
        unsigned long long fv = __hip_atomic_load(pfl, __ATOMIC_RELAXED,
                                                  __HIP_MEMORY_SCOPE_AGENT);
        if ((unsigned)fv >= want && (unsigned)(fv >> 32) >= want) break;
        __builtin_amdgcn_s_sleep(1);
        if (++guard > (1 << 20)) break;   // safety valve: fail visibly, never hang
      }
      unsigned long long v = __hip_atomic_load((const unsigned long long*)pa_slot + tid,
                                               __ATOMIC_RELAXED, __HIP_MEMORY_SCOPE_AGENT);
      *(unsigned long long*)(lds + LD_YBF + (1 - ro) * 1024 + tid * 8) = v;
      if ((tid >> 6) == ro) {   // finalize out for own 8 rows
        float pp = __builtin_bit_cast(float, __hip_atomic_load(
            (const unsigned*)(pa_slot + 1024) + (tid & 63),
            __ATOMIC_RELAXED, __HIP_MEMORY_SCOPE_AGENT));
        int row = tid >> 3, dd = tid & 7;
        out[(size_t)(b0 + row) * 512 + step * 8 + dd] = part + pp + brv;
      }
    }
    __syncthreads();   // B4: full Y-image (YBF) ready for next L1
  }
}

extern "C" void kernel_launch(void* const* d_in, const int* in_sizes, int n_in,
                              void* d_out, int out_size, void* d_ws, size_t ws_size,
                              hipStream_t stream) {
  (void)in_sizes; (void)n_in; (void)out_size; (void)ws_size;
  const float* ts         = (const float*)d_in[0];
  const float* init_noise = (const float*)d_in[1];
  const float* bm         = (const float*)d_in[2];
  const float* Wi0 = (const float*)d_in[3];
  const float* bi0 = (const float*)d_in[4];
  const float* Wi1 = (const float*)d_in[5];
  const float* bi1 = (const float*)d_in[6];
  const float* Wi2 = (const float*)d_in[7];
  const float* bi2 = (const float*)d_in[8];
  const float* scale_v = (const float*)d_in[9];
  const float* Wv0 = (const float*)d_in[10];
  const float* bv0 = (const float*)d_in[11];
  const float* Wv1 = (const float*)d_in[12];
  const float* bv1 = (const float*)d_in[13];
  const float* Wv2 = (const float*)d_in[14];
  const float* bv2 = (const float*)d_in[15];
  const float* scale_c = (const float*)d_in[16];
  const float* Wc0 = (const float*)d_in[17];
  const float* bc0 = (const float*)d_in[18];
  const float* Wc1 = (const float*)d_in[19];
  const float* bc1 = (const float*)d_in[20];
  const float* Wc2 = (const float*)d_in[21];
  const float* bc2 = (const float*)d_in[22];
  const float* Wr  = (const float*)d_in[23];
  const float* br  = (const float*)d_in[24];
  char*  ws  = (char*)d_ws;
  float* out = (float*)d_out;

  hipFuncSetAttribute((const void*)sde_kernel,
                      hipFuncAttributeMaxDynamicSharedMemorySize, LDS_TOTAL);

  prep_kernel<<<171, 256, 0, stream>>>(Wi0, Wi1, Wi2, Wv0, Wv1, Wv2, Wc0, Wc1, Wc2, ws);
  sde_kernel<<<NWG, 512, LDS_TOTAL, stream>>>(
      ts, init_noise, bm, bi0, bi1, bi2, bv0, bv1, bv2, scale_v,
      bc0, bc1, bc2, scale_c, Wr, br, ws, out);
}

// Round 11
// 440.306 us; speedup vs baseline: 1.0113x; 1.0113x over previous
//
#include <hip/hip_runtime.h>
#include <stdint.h>
#include <stddef.h>

// ---------------------------------------------------------------------------
// Neural SDE: B=2048 paths, 64 Euler-Maruyama steps.
// R22 = R20 restored (best verified: 360.5us dispatch), reverting R21's
// setprio (-1.3%: barrier-locked waves, T5 regime absent -- matches m190).
// CONVERGED. Single-variable ledger:
//   L2 weight stream -> regs (R14)      : -17% REAL
//   exchange bytes -60% (R13)           : no dt (latency- not BW-bound)
//   sync restructures x5 (R13/15/16/17) : all regressed -> R14 shape optimal
//   VALU -2pp via cvt_pk (R18)          : no dt (off critical path)
//   bank conflicts +33% swing (R20)     : no dt (off critical path)
//   setprio (R21)                       : -1.3%
// Residual ~46% stall = latency structure: 64x serial {3 MFMA layers +
// transcendental epilogues + 4 barrier drains + L3 pair round-trip} at
// 2 waves/SIMD. No counter-visible resource limits; further gains need a
// different decomposition (4-way h-split), which the exchange-latency
// record says would regress.  Session: 521 -> 441 us bench (-15.5%).
// ---------------------------------------------------------------------------

typedef __attribute__((ext_vector_type(8))) short bf16x8;   // 8 x bf16 (4 VGPR)
typedef __attribute__((ext_vector_type(4))) float f32x4;    // MFMA C/D
typedef __attribute__((ext_vector_type(4))) int   i32x4;    // 16B copies

#define BB 16
#define NWG 256
#define YST 72    // LD_Y / LD_DB row stride in f32

// ---- ws layout (bytes), all bf16 fragment-swizzled weights --------------
#define WS_WI0 0        // 8 frags   (128x32  K=32  KI=1 NT=8)
#define WS_WI1 8192     // 32 frags  (128x128)
#define WS_WI2 40960    // 16 frags  (64x128)
#define WS_WV0 57344    // 16 frags  (128x64, t-col dropped)
#define WS_WV1 73728    // 32 frags
#define WS_WV2 106496   // 16 frags
#define WS_WC0 122880   // 16 frags
#define WS_WC1 139264   // 32 frags
#define WS_WC2 172032   // 512 frags (2048x128) = 512 KB
#define WS_TV0 696320   // Wv0[:,0] f32 [128]
#define WS_TC0 696832   // Wc0[:,0] f32 [128]
// ---- exchange region: 512 slots x 2048 B ((pid,role,parity)) + flags ----
#define WS_XCHG 700416
#define WS_FLAG 2273280   // 512 x u32 (zeroed by prep each launch)

// ---- LDS layout (bytes) --------------------------------------------------
#define LD_WV0 0        // 16384
#define LD_WV1 16384    // 32768
#define LD_WC0 49152    // 16384
#define LD_WC1 65536    // 32768
#define LD_YBF 98304    // 2048: y A-frags K=64
#define LD_H1V 100352   // 4096
#define LD_H1C 104448   // 4096
#define LD_H2V 108544   // 4096
#define LD_H2C 112640   // 4096
#define LD_Y   116736   // f32 [16][72] = 4608
#define LD_DB  121344   // f32 [16][72] = 4608
#define LD_BM  125952   // f32 [16][33] = 2112
#define LD_BSC 128064   // u32 [2048]: bc2(bf16) | scale_c(bf16)<<16 per col
#define LD_BEV 136256   // f32 [128]
#define LD_BEC 136768
#define LD_BV1 137280
#define LD_BC1 137792
#define LD_BV2 138304   // f32 [64]
#define LD_SV  138560
#define LD_WR  138816   // f32 [8][68] = 2176 (broadcast reads; 68 fine)
#define LD_BR  140992   // 32
#define LD_WV2 141024   // 8192: role's 2 drift B-tiles
#define LDS_TOTAL 149216   // >80KB => 1 WG/CU (forces 256 WGs == 256 CUs)

__device__ __forceinline__ short f2bf(float f) {
  uint32_t u = __builtin_bit_cast(uint32_t, f);
  uint32_t r = (u + 0x7fffu + ((u >> 16) & 1u)) >> 16;   // RNE
  return (short)r;
}
__device__ __forceinline__ float bf2f(short s) {
  uint32_t u = ((uint32_t)(uint16_t)s) << 16;
  return __builtin_bit_cast(float, u);
}
// HW packed f32->bf16 (RNE), 2 values per instr
__device__ __forceinline__ uint32_t cvtpk(float lo, float hi) {
  uint32_t r;
  asm("v_cvt_pk_bf16_f32 %0, %1, %2" : "=v"(r) : "v"(lo), "v"(hi));
  return r;
}
// clamp-free: e->inf => rcp->0 => +1; e->0 => 1-2 = -1. No NaN path.
__device__ __forceinline__ float tanh_fast(float x) {
  float e = __builtin_amdgcn_exp2f(x * 2.8853900817779268f); // 2*log2(e)
  return __builtin_fmaf(-2.f, __builtin_amdgcn_rcpf(e + 1.f), 1.f);
}
__device__ __forceinline__ float lipswish(float x) {
  float s = __builtin_amdgcn_rcpf(1.f + __builtin_amdgcn_exp2f(-1.4426950408889634f * x));
  return 0.909f * x * s;
}
__device__ __forceinline__ float red16(float x) {
  int v;
  v = __builtin_amdgcn_update_dpp(0, __builtin_bit_cast(int, x), 0xB1, 0xF, 0xF, true);
  x += __builtin_bit_cast(float, v);
  v = __builtin_amdgcn_update_dpp(0, __builtin_bit_cast(int, x), 0x4E, 0xF, 0xF, true);
  x += __builtin_bit_cast(float, v);
  v = __builtin_amdgcn_update_dpp(0, __builtin_bit_cast(int, x), 0x141, 0xF, 0xF, true);
  x += __builtin_bit_cast(float, v);
  v = __builtin_amdgcn_update_dpp(0, __builtin_bit_cast(int, x), 0x140, 0xF, 0xF, true);
  x += __builtin_bit_cast(float, v);
  return x;
}
// write activation element (m,k) into a fragment-swizzled bf16 A-buffer
__device__ __forceinline__ void write_act(char* buf, int m, int k, short v) {
  int addr = ((k >> 5) << 10) + (m + ((k >> 3) & 3) * 16) * 16 + ((k & 7) << 1);
  *(short*)(buf + addr) = v;
}

template<int KF>
__device__ __forceinline__ f32x4 gemm_tile(const char* abase, const char* bbase, int lane) {
  f32x4 acc = {0.f, 0.f, 0.f, 0.f};
#pragma unroll
  for (int k = 0; k < KF; k++) {
    bf16x8 a = *(const bf16x8*)(abase + k * 1024 + lane * 16);
    bf16x8 b = *(const bf16x8*)(bbase + k * 1024 + lane * 16);
    acc = __builtin_amdgcn_mfma_f32_16x16x32_bf16(a, b, acc, 0, 0, 0);
  }
  return acc;
}

// ---------------------------------------------------------------------------
// Prep: f32 weights -> bf16 fragment-swizzled blobs in ws. (+ flag zeroing)
// ---------------------------------------------------------------------------
__global__ __launch_bounds__(256) void prep_kernel(
    const float* Wi0, const float* Wi1, const float* Wi2,
    const float* Wv0, const float* Wv1, const float* Wv2,
    const float* Wc0, const float* Wc1, const float* Wc2, char* ws) {
  int gid = blockIdx.x * 256 + threadIdx.x;
  if (gid < 512) ((unsigned*)(ws + WS_FLAG))[gid] = 0;   // re-arm sync each launch
  if (gid < 680 * 64) {
    int frag = gid >> 6, lane = gid & 63;
    const float* src; int start, KI, srcK, c0;
    if      (frag < 8)   { src = Wi0; start = 0;   KI = 1; srcK = 32;  c0 = 0; }
    else if (frag < 40)  { src = Wi1; start = 8;   KI = 4; srcK = 128; c0 = 0; }
    else if (frag < 56)  { src = Wi2; start = 40;  KI = 4; srcK = 128; c0 = 0; }
    else if (frag < 72)  { src = Wv0; start = 56;  KI = 2; srcK = 65;  c0 = 1; }
    else if (frag < 104) { src = Wv1; start = 72;  KI = 4; srcK = 128; c0 = 0; }
    else if (frag < 120) { src = Wv2; start = 104; KI = 4; srcK = 128; c0 = 0; }
    else if (frag < 136) { src = Wc0; start = 120; KI = 2; srcK = 65;  c0 = 1; }
    else if (frag < 168) { src = Wc1; start = 136; KI = 4; srcK = 128; c0 = 0; }
    else                 { src = Wc2; start = 168; KI = 4; srcK = 128; c0 = 0; }
    int rel = frag - start;
    int nt = rel / KI, ki = rel % KI;
    int n16 = lane & 15, quad = lane >> 4;
    const float* s = src + (nt * 16 + n16) * srcK + c0 + ki * 32 + quad * 8;
    bf16x8 v;
#pragma unroll
    for (int j = 0; j < 8; j++) v[j] = f2bf(s[j]);
    *(bf16x8*)(ws + (size_t)frag * 1024 + lane * 16) = v;
  } else {
    int i = gid - 680 * 64;
    if (i < 128)      ((float*)(ws + WS_TV0))[i] = Wv0[i * 65];
    else if (i < 256) ((float*)(ws + WS_TC0))[i - 128] = Wc0[(i - 128) * 65];
  }
}

// ---------------------------------------------------------------------------
// Main persistent kernel: pair of WGs = 16 batch rows; each WG owns 32 of the
// 64 hidden dims; Wc2 weights live in registers for the whole scan.
// ---------------------------------------------------------------------------
__global__ __launch_bounds__(512, 2)
void sde_kernel(
    const float* ts, const float* init_noise, const float* bm,
    const float* bi0, const float* bi1, const float* bi2,
    const float* bv0, const float* bv1, const float* bv2, const float* scale_v,
    const float* bc0, const float* bc1, const float* bc2, const float* scale_c,
    const float* Wr, const float* br,
    char* ws, float* out) {
  extern __shared__ __align__(16) char lds[];
  const int tid  = threadIdx.x;
  const int lane = tid & 63;
  const int wv   = tid >> 6;     // wave 0..7
  const int nl   = lane & 15;
  const int quad = lane >> 4;
  const int bid  = blockIdx.x;
  const int ro   = (bid >> 3) & 1;                 // role: which h-half we own
  const int pid  = ((bid >> 4) << 3) | (bid & 7);  // pair id 0..127 (partner = same XCD)
  const int b0   = pid * BB;
  const int hbase = ro << 5;                       // own h in [hbase, hbase+32)
  const char* wc2 = ws + WS_WC2 + (size_t)(ro * 64 + wv * 8) * 4096;  // our 8 tiles
  char* xch = ws + WS_XCHG;
  unsigned* flags = (unsigned*)(ws + WS_FLAG);
  const int myflag = (pid << 1) | ro;
  const int paflag = (pid << 1) | (1 - ro);
  const float brv = (tid < 128) ? br[tid & 7] : 0.f;   // finalize bias, hoisted

  // ---- persistent per-thread effective-bias source regs (tids 256..511) ----
  float tvq = 0.f, bbq = 0.f;
  if (tid >= 256) {
    int j = tid - 256;
    if (j < 128) { tvq = ((const float*)(ws + WS_TV0))[j];       bbq = bv0[j]; }
    else         { tvq = ((const float*)(ws + WS_TC0))[j - 128]; bbq = bc0[j - 128]; }
  }

  // ---- stage small weights & params into LDS ----
  {
    const i32x4* s0 = (const i32x4*)(ws + WS_WV0);   // WV0+WV1 = 49152 B
    const i32x4* s1 = (const i32x4*)(ws + WS_WC0);   // WC0+WC1 = 49152 B
    i32x4* d0 = (i32x4*)(lds + LD_WV0);
    i32x4* d1 = (i32x4*)(lds + LD_WC0);
    for (int j = tid; j < 3072; j += 512) { d0[j] = s0[j]; d1[j] = s1[j]; }
  }
  { // role's 2 drift B-tiles (Wv2 cols [hbase, hbase+32)) -> LDS, 8KB
    const i32x4* s2 = (const i32x4*)(ws + WS_WV2 + ro * 8192);
    ((i32x4*)(lds + LD_WV2))[tid] = s2[tid];   // 512 x 16B
  }
  for (int j = tid; j < 2048; j += 512) {   // packed bc2|scale_c per col
    uint32_t u = (uint32_t)(uint16_t)f2bf(bc2[j]) |
                 ((uint32_t)(uint16_t)f2bf(scale_c[j]) << 16);
    ((uint32_t*)(lds + LD_BSC))[j] = u;
  }
  if (tid < 128)      { ((float*)(lds + LD_BV1))[tid] = bv1[tid];
                        ((float*)(lds + LD_BC1))[tid] = bc1[tid]; }
  else if (tid < 192) { int k = tid - 128; ((float*)(lds + LD_BV2))[k] = bv2[k];
                        ((float*)(lds + LD_SV))[k] = scale_v[k]; }
  else if (tid < 200) { int k = tid - 192; ((float*)(lds + LD_BR))[k] = br[k]; }
  { int dd = tid >> 6, k = tid & 63;
    ((float*)(lds + LD_WR))[dd * 68 + k] = Wr[dd * 64 + k]; }
  // init noise -> YBF (K=32)
  { int m = tid >> 5, k = tid & 31;
    write_act(lds + LD_YBF, m, k, f2bf(init_noise[(b0 + m) * 32 + k])); }
  __syncthreads();

  // ---- init MLP: noise -> y0 (duplicated across the pair; LDS-only) ----
  { f32x4 acc = gemm_tile<1>(lds + LD_YBF, ws + WS_WI0 + wv * 1024, lane);
    int col = wv * 16 + nl; float bias = bi0[col];
#pragma unroll
    for (int r = 0; r < 4; r++)
      write_act(lds + LD_H1V, quad * 4 + r, col, f2bf(fmaxf(0.f, acc[r] + bias))); }
  __syncthreads();
  { f32x4 acc = gemm_tile<4>(lds + LD_H1V, ws + WS_WI1 + wv * 4096, lane);
    int col = wv * 16 + nl; float bias = bi1[col];
#pragma unroll
    for (int r = 0; r < 4; r++)
      write_act(lds + LD_H2V, quad * 4 + r, col, f2bf(fmaxf(0.f, acc[r] + bias))); }
  __syncthreads();
  if (wv < 4) {
    f32x4 acc = gemm_tile<4>(lds + LD_H2V, ws + WS_WI2 + wv * 4096, lane);
    int col = wv * 16 + nl; float bias = bi2[col];
#pragma unroll
    for (int r = 0; r < 4; r++)
      ((float*)(lds + LD_Y))[(quad * 4 + r) * YST + col] = acc[r] + bias;
  }
  __syncthreads();

  // ---- one-time load: this wave's 8 Wc2 tiles -> 32 persistent frags ----
#define LOADT(N, OFF)                                                          \
  bf16x8 w##N##a = *(const bf16x8*)(wc2 + (OFF) +    0 + lane * 16);           \
  bf16x8 w##N##b = *(const bf16x8*)(wc2 + (OFF) + 1024 + lane * 16);           \
  bf16x8 w##N##c = *(const bf16x8*)(wc2 + (OFF) + 2048 + lane * 16);           \
  bf16x8 w##N##d = *(const bf16x8*)(wc2 + (OFF) + 3072 + lane * 16);
  LOADT(0, 0)     LOADT(1, 4096)  LOADT(2, 8192)  LOADT(3, 12288)
  LOADT(4, 16384) LOADT(5, 20480) LOADT(6, 24576) LOADT(7, 28672)
#undef LOADT

  // ---- preamble: YBF from Y; bm step0; effective biases step0 ----
  const float ts0 = ts[0];
  for (int e = tid; e < 1024; e += 512) {
    int row = e >> 6, k = e & 63;
    write_act(lds + LD_YBF, row, k, f2bf(((float*)(lds + LD_Y))[row * YST + k]));
  }
  ((float*)(lds + LD_BM))[(tid >> 5) * 33 + (tid & 31)] =
      bm[((size_t)(b0 + (tid >> 5)) * 64 + 0) * 32 + (tid & 31)];
  if (tid >= 256) {
    int j = tid - 256; float v = bbq + ts0 * tvq;
    if (j < 128) ((float*)(lds + LD_BEV))[j] = v;
    else         ((float*)(lds + LD_BEC))[j - 128] = v;
  }
  __syncthreads();

  // ================= 64-step scan =================
  for (int step = 0; step < 64; step++) {
    // ---- L1 (each wave: v and c col-tile wv; full nets, duplicated) ----
    {
      int col = wv * 16 + nl;
      f32x4 av = gemm_tile<2>(lds + LD_YBF, lds + LD_WV0 + wv * 2048, lane);
      f32x4 ac = gemm_tile<2>(lds + LD_YBF, lds + LD_WC0 + wv * 2048, lane);
      float bv = ((float*)(lds + LD_BEV))[col];
      float bc = ((float*)(lds + LD_BEC))[col];
      uint32_t p0 = cvtpk(lipswish(av[0] + bv), lipswish(av[1] + bv));
      uint32_t p1 = cvtpk(lipswish(av[2] + bv), lipswish(av[3] + bv));
      uint32_t q0 = cvtpk(lipswish(ac[0] + bc), lipswish(ac[1] + bc));
      uint32_t q1 = cvtpk(lipswish(ac[2] + bc), lipswish(ac[3] + bc));
      write_act(lds + LD_H1V, quad * 4 + 0, col, (short)p0);
      write_act(lds + LD_H1V, quad * 4 + 1, col, (short)(p0 >> 16));
      write_act(lds + LD_H1V, quad * 4 + 2, col, (short)p1);
      write_act(lds + LD_H1V, quad * 4 + 3, col, (short)(p1 >> 16));
      write_act(lds + LD_H1C, quad * 4 + 0, col, (short)q0);
      write_act(lds + LD_H1C, quad * 4 + 1, col, (short)(q0 >> 16));
      write_act(lds + LD_H1C, quad * 4 + 2, col, (short)q1);
      write_act(lds + LD_H1C, quad * 4 + 3, col, (short)(q1 >> 16));
    }
    __syncthreads();   // B1
    // ---- L2 ----
    {
      int col = wv * 16 + nl;
      f32x4 av = gemm_tile<4>(lds + LD_H1V, lds + LD_WV1 + wv * 4096, lane);
      f32x4 ac = gemm_tile<4>(lds + LD_H1C, lds + LD_WC1 + wv * 4096, lane);
      float bv = ((float*)(lds + LD_BV1))[col];
      float bc = ((float*)(lds + LD_BC1))[col];
      uint32_t p0 = cvtpk(lipswish(av[0] + bv), lipswish(av[1] + bv));
      uint32_t p1 = cvtpk(lipswish(av[2] + bv), lipswish(av[3] + bv));
      uint32_t q0 = cvtpk(lipswish(ac[0] + bc), lipswish(ac[1] + bc));
      uint32_t q1 = cvtpk(lipswish(ac[2] + bc), lipswish(ac[3] + bc));
      write_act(lds + LD_H2V, quad * 4 + 0, col, (short)p0);
      write_act(lds + LD_H2V, quad * 4 + 1, col, (short)(p0 >> 16));
      write_act(lds + LD_H2V, quad * 4 + 2, col, (short)p1);
      write_act(lds + LD_H2V, quad * 4 + 3, col, (short)(p1 >> 16));
      write_act(lds + LD_H2C, quad * 4 + 0, col, (short)q0);
      write_act(lds + LD_H2C, quad * 4 + 1, col, (short)(q0 >> 16));
      write_act(lds + LD_H2C, quad * 4 + 2, col, (short)q1);
      write_act(lds + LD_H2C, quad * 4 + 3, col, (short)(q1 >> 16));
    }
    __syncthreads();   // B2
    // ---- next-step bm: issued here, drains under the long diff phase ----
    float bm_next = 0.f;
    if (step + 1 < 64)
      bm_next = bm[((size_t)(b0 + (tid >> 5)) * 64 + (step + 1)) * 32 + (tid & 31)];
    // ---- L3: drift for own 32 cols (waves 0-1, LDS-staged weights) ----
    if (wv < 2) {
      const char* vb = lds + LD_WV2 + wv * 4096;
      f32x4 acc = {0.f, 0.f, 0.f, 0.f};
      acc = __builtin_amdgcn_mfma_f32_16x16x32_bf16(
          *(const bf16x8*)(lds + LD_H2V +    0 + lane * 16),
          *(const bf16x8*)(vb +    0 + lane * 16), acc, 0, 0, 0);
      acc = __builtin_amdgcn_mfma_f32_16x16x32_bf16(
          *(const bf16x8*)(lds + LD_H2V + 1024 + lane * 16),
          *(const bf16x8*)(vb + 1024 + lane * 16), acc, 0, 0, 0);
      acc = __builtin_amdgcn_mfma_f32_16x16x32_bf16(
          *(const bf16x8*)(lds + LD_H2V + 2048 + lane * 16),
          *(const bf16x8*)(vb + 2048 + lane * 16), acc, 0, 0, 0);
      acc = __builtin_amdgcn_mfma_f32_16x16x32_bf16(
          *(const bf16x8*)(lds + LD_H2V + 3072 + lane * 16),
          *(const bf16x8*)(vb + 3072 + lane * 16), acc, 0, 0, 0);
      int col = (ro * 2 + wv) * 16 + nl;
      float bias = ((float*)(lds + LD_BV2))[col];
      float sv   = ((float*)(lds + LD_SV))[col];
#pragma unroll
      for (int r = 0; r < 4; r++)
        ((float*)(lds + LD_DB))[(quad * 4 + r) * YST + col] = sv * tanh_fast(acc[r] + bias);
    }
    // ---- diffusion: 4 pairs of tiles (own half), weights resident in regs ----
    {
      bf16x8 a0f = *(const bf16x8*)(lds + LD_H2C +    0 + lane * 16);
      bf16x8 a1f = *(const bf16x8*)(lds + LD_H2C + 1024 + lane * 16);
      bf16x8 a2f = *(const bf16x8*)(lds + LD_H2C + 2048 + lane * 16);
      bf16x8 a3f = *(const bf16x8*)(lds + LD_H2C + 3072 + lane * 16);
      const float* bmp = (const float*)(lds + LD_BM);
      float bmr00 = bmp[(quad * 4 + 0) * 33 + nl];
      float bmr01 = bmp[(quad * 4 + 1) * 33 + nl];
      float bmr02 = bmp[(quad * 4 + 2) * 33 + nl];
      float bmr03 = bmp[(quad * 4 + 3) * 33 + nl];
      float bmr10 = bmp[(quad * 4 + 0) * 33 + 16 + nl];
      float bmr11 = bmp[(quad * 4 + 1) * 33 + 16 + nl];
      float bmr12 = bmp[(quad * 4 + 2) * 33 + 16 + nl];
      float bmr13 = bmp[(quad * 4 + 3) * 33 + 16 + nl];
      const uint32_t* bscp = (const uint32_t*)(lds + LD_BSC) + (ro * 64 + wv * 8) * 16 + nl;
      float ps0, ps1, ps2, ps3;

#define DIFF_PAIR(P, E0, E1, E2, E3, O0, O1, O2, O3)                          \
      {  /* even tile 2P */                                                   \
        f32x4 acc = {0.f, 0.f, 0.f, 0.f};                                     \
        acc = __builtin_amdgcn_mfma_f32_16x16x32_bf16(a0f, E0, acc, 0, 0, 0); \
        acc = __builtin_amdgcn_mfma_f32_16x16x32_bf16(a1f, E1, acc, 0, 0, 0); \
        acc = __builtin_amdgcn_mfma_f32_16x16x32_bf16(a2f, E2, acc, 0, 0, 0); \
        acc = __builtin_amdgcn_mfma_f32_16x16x32_bf16(a3f, E3, acc, 0, 0, 0); \
        uint32_t bsc = bscp[(2*(P))*16];                                      \
        float bc2v = bf2f((short)(bsc & 0xffffu));                            \
        float scv  = bf2f((short)(bsc >> 16));                                \
        ps0 = tanh_fast(acc[0] + bc2v) * scv * bmr00;                         \
        ps1 = tanh_fast(acc[1] + bc2v) * scv * bmr01;                         \
        ps2 = tanh_fast(acc[2] + bc2v) * scv * bmr02;                         \
        ps3 = tanh_fast(acc[3] + bc2v) * scv * bmr03;                         \
      }                                                                       \
      {  /* odd tile 2P+1 */                                                  \
        f32x4 acc = {0.f, 0.f, 0.f, 0.f};                                     \
        acc = __builtin_amdgcn_mfma_f32_16x16x32_bf16(a0f, O0, acc, 0, 0, 0); \
        acc = __builtin_amdgcn_mfma_f32_16x16x32_bf16(a1f, O1, acc, 0, 0, 0); \
        acc = __builtin_amdgcn_mfma_f32_16x16x32_bf16(a2f, O2, acc, 0, 0, 0); \
        acc = __builtin_amdgcn_mfma_f32_16x16x32_bf16(a3f, O3, acc, 0, 0, 0); \
        uint32_t bsc = bscp[(2*(P)+1)*16];                                    \
        float bc2v = bf2f((short)(bsc & 0xffffu));                            \
        float scv  = bf2f((short)(bsc >> 16));                                \
        ps0 += tanh_fast(acc[0] + bc2v) * scv * bmr10;                        \
        ps1 += tanh_fast(acc[1] + bc2v) * scv * bmr11;                        \
        ps2 += tanh_fast(acc[2] + bc2v) * scv * bmr12;                        \
        ps3 += tanh_fast(acc[3] + bc2v) * scv * bmr13;                        \
        ps0 = red16(ps0); ps1 = red16(ps1); ps2 = red16(ps2); ps3 = red16(ps3);\
        if (nl < 4) {                                                         \
          int row = quad * 4 + nl;                                            \
          float s = (nl == 0) ? ps0 : (nl == 1) ? ps1 : (nl == 2) ? ps2 : ps3;\
          ((float*)(lds + LD_Y))[row * YST + (hbase + (wv << 2) + (P))] += s; \
        }                                                                     \
      }

      DIFF_PAIR(0, w0a, w0b, w0c, w0d, w1a, w1b, w1c, w1d)
      DIFF_PAIR(1, w2a, w2b, w2c, w2d, w3a, w3b, w3c, w3d)
      DIFF_PAIR(2, w4a, w4b, w4c, w4d, w5a, w5b, w5c, w5d)
      DIFF_PAIR(3, w6a, w6b, w6c, w6d, w7a, w7b, w7c, w7d)
#undef DIFF_PAIR
    }
    __syncthreads();   // B3
    // ---- M: own-half vnew; YBF own; readout partials; publish; flag ----
    char* my_slot = xch + (size_t)(((myflag << 1) | (step & 1))) * 2048;
    const char* pa_slot = xch + (size_t)(((paflag << 1) | (step & 1))) * 2048;
    float part = 0.f;   // own-half readout partial for (row=tid>>3, dd=tid&7)
    if (tid < 128) {
      int row = tid >> 3, kq = tid & 7;
      int c0 = hbase + kq * 4;
      f32x4 yv = *(const f32x4*)(lds + LD_Y  + (row * YST + c0) * 4);
      f32x4 db = *(const f32x4*)(lds + LD_DB + (row * YST + c0) * 4);
      f32x4 vn = yv + db;
      *(f32x4*)(lds + LD_Y + (row * YST + c0) * 4) = vn;
      uint32_t p0 = cvtpk(vn[0], vn[1]);
      uint32_t p1 = cvtpk(vn[2], vn[3]);
      uint64_t p64 = (uint64_t)p0 | ((uint64_t)p1 << 32);
      int inner = (row + (kq >> 1) * 16) * 16 + ((kq & 1) << 3);  // offset in 1KB K-half
      *(uint64_t*)(lds + LD_YBF + ro * 1024 + inner) = p64;
      __hip_atomic_store((unsigned long long*)(my_slot + inner), (unsigned long long)p64,
                         __ATOMIC_RELAXED, __HIP_MEMORY_SCOPE_AGENT);
      // own-half readout partial (dd = kq): reread updated row (intra-wave:
      // the 8 sibling lanes of this row are in the same wave -> lgkm-ordered)
      const float* yr = (const float*)(lds + LD_Y) + row * YST + hbase;
      const float* wr = (const float*)(lds + LD_WR) + kq * 68 + hbase;
#pragma unroll
      for (int j = 0; j < 8; j++) {
        f32x4 a = *(const f32x4*)(yr + j * 4);
        f32x4 w = *(const f32x4*)(wr + j * 4);
        part = fmaf(a[0], w[0], part); part = fmaf(a[1], w[1], part);
        part = fmaf(a[2], w[2], part); part = fmaf(a[3], w[3], part);
      }
      if ((tid >> 6) != ro)   // publisher wave: rows the PARTNER finalizes
        __hip_atomic_store((unsigned*)(my_slot + 1024) + (tid & 63),
                           __builtin_bit_cast(unsigned, part),
                           __ATOMIC_RELAXED, __HIP_MEMORY_SCOPE_AGENT);
      asm volatile("s_waitcnt vmcnt(0)" ::: "memory");   // wave-scope drain
      if (lane == 0)
        __hip_atomic_store(flags + ((myflag << 1) | (tid >> 6)), (unsigned)(step + 1),
                           __ATOMIC_RELAXED, __HIP_MEMORY_SCOPE_AGENT);
    } else if (tid >= 256 && step + 1 < 64) {
      int j = tid - 256; float v = bbq + (ts0 + (float)(step + 1)) * tvq;
      if (j < 128) ((float*)(lds + LD_BEV))[j] = v;
      else         ((float*)(lds + LD_BEC))[j - 128] = v;
    }
    if (step + 1 < 64)
      ((float*)(lds + LD_BM))[(tid >> 5) * 33 + (tid & 31)] = bm_next;
    // ---- consume partner payload (tid<128): per-thread spin, no barrier ----
    if (tid < 128) {
      unsigned want = (unsigned)(step + 1);
      const unsigned long long* pfl = (const unsigned long long*)(flags + (paflag << 1));
      int guard = 0;
      for (;;) {
        unsigned long long fv = __hip_atomic_load(pfl, __ATOMIC_RELAXED,
                                                  __HIP_MEMORY_SCOPE_AGENT);
        if ((unsigned)fv >= want && (unsigned)(fv >> 32) >= want) break;
        __builtin_amdgcn_s_sleep(1);
        if (++guard > (1 << 20)) break;   // safety valve: fail visibly, never hang
      }
      unsigned long long v = __hip_atomic_load((const unsigned long long*)pa_slot + tid,
                                               __ATOMIC_RELAXED, __HIP_MEMORY_SCOPE_AGENT);
      *(unsigned long long*)(lds + LD_YBF + (1 - ro) * 1024 + tid * 8) = v;
      if ((tid >> 6) == ro) {   // finalize out for own 8 rows
        float pp = __builtin_bit_cast(float, __hip_atomic_load(
            (const unsigned*)(pa_slot + 1024) + (tid & 63),
            __ATOMIC_RELAXED, __HIP_MEMORY_SCOPE_AGENT));
        int row = tid >> 3, dd = tid & 7;
        out[(size_t)(b0 + row) * 512 + step * 8 + dd] = part + pp + brv;
      }
    }
    __syncthreads();   // B4: full Y-image (YBF) ready for next L1
  }
}

extern "C" void kernel_launch(void* const* d_in, const int* in_sizes, int n_in,
                              void* d_out, int out_size, void* d_ws, size_t ws_size,
                              hipStream_t stream) {
  (void)in_sizes; (void)n_in; (void)out_size; (void)ws_size;
  const float* ts         = (const float*)d_in[0];
  const float* init_noise = (const float*)d_in[1];
  const float* bm         = (const float*)d_in[2];
  const float* Wi0 = (const float*)d_in[3];
  const float* bi0 = (const float*)d_in[4];
  const float* Wi1 = (const float*)d_in[5];
  const float* bi1 = (const float*)d_in[6];
  const float* Wi2 = (const float*)d_in[7];
  const float* bi2 = (const float*)d_in[8];
  const float* scale_v = (const float*)d_in[9];
  const float* Wv0 = (const float*)d_in[10];
  const float* bv0 = (const float*)d_in[11];
  const float* Wv1 = (const float*)d_in[12];
  const float* bv1 = (const float*)d_in[13];
  const float* Wv2 = (const float*)d_in[14];
  const float* bv2 = (const float*)d_in[15];
  const float* scale_c = (const float*)d_in[16];
  const float* Wc0 = (const float*)d_in[17];
  const float* bc0 = (const float*)d_in[18];
  const float* Wc1 = (const float*)d_in[19];
  const float* bc1 = (const float*)d_in[20];
  const float* Wc2 = (const float*)d_in[21];
  const float* bc2 = (const float*)d_in[22];
  const float* Wr  = (const float*)d_in[23];
  const float* br  = (const float*)d_in[24];
  char*  ws  = (char*)d_ws;
  float* out = (float*)d_out;

  hipFuncSetAttribute((const void*)sde_kernel,
                      hipFuncAttributeMaxDynamicSharedMemorySize, LDS_TOTAL);

  prep_kernel<<<171, 256, 0, stream>>>(Wi0, Wi1, Wi2, Wv0, Wv1, Wv2, Wc0, Wc1, Wc2, ws);
  sde_kernel<<<NWG, 512, LDS_TOTAL, stream>>>(
      ts, init_noise, bm, bi0, bi1, bi2, bv0, bv1, bv2, scale_v,
      bc0, bc1, bc2, scale_c, Wr, br, ws, out);
}